// Round 1
// baseline (1091.272 us; speedup 1.0000x reference)
//
#include <hip/hip_runtime.h>
#include <hip/hip_bf16.h>
#include <math.h>

// ---------------------------------------------------------------------------
// FakeNewsAttention: 8-head attention over S=50000 sources, B=1024, D=128.
// Design (round 1):
//  k_qproj : Q[b,h,:] = (user_emb[uid[b]] @ Wcm[h]) / sqrt(D)  -> bf16
//  k_convM : source_emb -> bf16 row-major, zero-padded to S_PAD rows
//  k_transM: bf16 transpose -> MbfT[D][S_PAD]  (for PV B-operand staging)
//  k_attn  : flash-style, NO online-max needed (softmax arg in [0,~4]):
//            per (s-chunk, b-tile of 32) block, 8 waves = 8 heads,
//            accumulate sumE and acc = sum_s exp(relu(qk)*A) * M[s]
//  k_reduce: combine chunk partials, divide -> hhat[b][h*128+e]
//  k_final : m = hhat @ W1 ; out = elu(m) + Xu
// ---------------------------------------------------------------------------

#define S_TOT 50000
#define S_PAD 50304   // multiple of 64
#define DDIM 128
#define NHEAD 8
#define NB 1024
#define BQ 32         // batch rows per attention block
#define SN 32         // sources per inner iteration
#define NCH 8         // S chunks
#define SCHUNK 6272   // ceil-ish: 8*6272 = 50176 >= 50000, multiple of 32
#define NBT 32        // NB / BQ

typedef __bf16 v8bf __attribute__((ext_vector_type(8)));
typedef float v4f __attribute__((ext_vector_type(4)));

union U4BF { uint4 u; v8bf b; };

__device__ inline unsigned short f2bf(float f) {
  union { float f; unsigned u; } v; v.f = f;
  unsigned r = (v.u + 0x7FFFu + ((v.u >> 16) & 1u)) >> 16;
  return (unsigned short)r;
}

// ---------------------------------------------------------------- k_qproj
__global__ void k_qproj(const int* __restrict__ uid, const float* __restrict__ user_emb,
                        const float* __restrict__ Wcm, unsigned short* __restrict__ Qbf) {
  int bh = blockIdx.x;          // b*8 + h
  int b = bh >> 3, h = bh & 7;
  int e = threadIdx.x;          // 0..127
  int u = uid[b];
  const float* xu = user_emb + (long)u * DDIM;
  const float* w = Wcm + (long)h * DDIM * DDIM + e;
  float acc = 0.f;
#pragma unroll 16
  for (int d = 0; d < DDIM; ++d) acc += xu[d] * w[(long)d * DDIM];
  Qbf[(long)bh * DDIM + e] = f2bf(acc * 0.08838834764831845f); // 1/sqrt(128)
}

// ---------------------------------------------------------------- k_convM
__global__ void k_convM(const float* __restrict__ M, unsigned short* __restrict__ Mbf) {
  long i = (long)(blockIdx.x * 256 + threadIdx.x) * 8;
  if (i >= (long)S_PAD * DDIM) return;
  union { unsigned short s[8]; uint4 u; } o;
  if (i < (long)S_TOT * DDIM) {
    const float4* p = (const float4*)(M + i);
    float4 a = p[0], b = p[1];
    o.s[0] = f2bf(a.x); o.s[1] = f2bf(a.y); o.s[2] = f2bf(a.z); o.s[3] = f2bf(a.w);
    o.s[4] = f2bf(b.x); o.s[5] = f2bf(b.y); o.s[6] = f2bf(b.z); o.s[7] = f2bf(b.w);
  } else {
    o.u.x = 0; o.u.y = 0; o.u.z = 0; o.u.w = 0;
  }
  *(uint4*)(Mbf + i) = o.u;
}

// ---------------------------------------------------------------- k_transM
__global__ void k_transM(const unsigned short* __restrict__ Mbf, unsigned short* __restrict__ MbfT) {
  __shared__ unsigned short tile[64][65];
  int s0 = blockIdx.x * 64, d0 = blockIdx.y * 64;
  int t = threadIdx.x;
#pragma unroll
  for (int it = 0; it < 16; ++it) {
    int flat = t + 256 * it;           // 0..4095
    int sl = flat >> 6, dl = flat & 63;
    tile[sl][dl] = Mbf[(long)(s0 + sl) * DDIM + d0 + dl];
  }
  __syncthreads();
#pragma unroll
  for (int it = 0; it < 16; ++it) {
    int flat = t + 256 * it;
    int dl = flat >> 6, sl = flat & 63;
    MbfT[(long)(d0 + dl) * S_PAD + s0 + sl] = tile[sl][dl];
  }
}

// ---------------------------------------------------------------- k_attn
// block: 512 threads = 8 waves; wave w == head w; BQ=32 batch rows.
// m-row index within block: m = h*32 + bl (bl = batch-local row).
__launch_bounds__(512, 2)
__global__ void k_attn(const int* __restrict__ uid_g, const float* __restrict__ A_us,
                       const unsigned short* __restrict__ Qbf,
                       const unsigned short* __restrict__ Mbf,
                       const unsigned short* __restrict__ MbfT,
                       float* __restrict__ part_acc, float* __restrict__ part_sum) {
  // padded LDS (>=16B aligned rows; strides chosen for <=2-way bank conflicts)
  __shared__ __align__(16) unsigned short lds_M[SN][136];    // [s][d]
  __shared__ __align__(16) unsigned short lds_Mt[DDIM][40];  // [d][s]
  __shared__ __align__(16) unsigned short lds_P[256][40];    // [m][s]
  __shared__ __align__(16) float lds_At[SN][36];             // [s][bl]  (A transposed)
  __shared__ int lds_uid[BQ];

  int ch = blockIdx.x;   // 0..NCH-1
  int bt = blockIdx.y;   // 0..NBT-1
  int tid = threadIdx.x;
  int w = tid >> 6;          // wave id == head
  int lane = tid & 63;
  int q = lane >> 4, li = lane & 15;

  if (tid < BQ) lds_uid[tid] = uid_g[bt * BQ + tid];

  // Q fragments (A-operand): qf[mt][k] -> Q[b0 + mt*16 + li][k*32 + q*8 .. +7]
  U4BF qf[2][4];
#pragma unroll
  for (int mt = 0; mt < 2; ++mt)
#pragma unroll
    for (int k = 0; k < 4; ++k) {
      int b = bt * BQ + mt * 16 + li;
      qf[mt][k].u = *(const uint4*)(Qbf + ((long)(b * NHEAD + w) * DDIM + k * 32 + q * 8));
    }

  v4f zero4 = {0.f, 0.f, 0.f, 0.f};
  v4f acc[2][8];
#pragma unroll
  for (int mt = 0; mt < 2; ++mt)
#pragma unroll
    for (int dt = 0; dt < 8; ++dt) acc[mt][dt] = zero4;
  float sE[2][4] = {{0.f,0.f,0.f,0.f},{0.f,0.f,0.f,0.f}};

  __syncthreads();

  int s_beg = ch * SCHUNK;
  int s_fin = s_beg + SCHUNK;
  if (s_fin > S_TOT) s_fin = S_TOT;

  for (int s0 = s_beg; s0 < s_fin; s0 += SN) {
    // ---- stage M (row), Mt (transposed), A (transposed) ----
    {
      int sl = tid >> 4, d = (tid & 15) * 8;
      uint4 mv = *(const uint4*)(Mbf + (long)(s0 + sl) * DDIM + d);
      *(uint4*)&lds_M[sl][d] = mv;

      int dd2 = tid >> 2, pp = (tid & 3) * 8;
      uint4 tv = *(const uint4*)(MbfT + (long)dd2 * S_PAD + s0 + pp);
      *(uint4*)&lds_Mt[dd2][pp] = tv;

      if (tid < 256) {
        int bl = tid >> 3, sq = (tid & 7) * 4;
        const float* arow = A_us + (long)lds_uid[bl] * S_TOT;
        int sg = s0 + sq;
        float4 av;
        if (sg + 3 < S_TOT) {
          av = *(const float4*)(arow + sg);
        } else {
          av.x = (sg + 0 < S_TOT) ? arow[sg + 0] : 0.f;
          av.y = (sg + 1 < S_TOT) ? arow[sg + 1] : 0.f;
          av.z = (sg + 2 < S_TOT) ? arow[sg + 2] : 0.f;
          av.w = (sg + 3 < S_TOT) ? arow[sg + 3] : 0.f;
        }
        lds_At[sq + 0][bl] = av.x;
        lds_At[sq + 1][bl] = av.y;
        lds_At[sq + 2][bl] = av.z;
        lds_At[sq + 3][bl] = av.w;
      }
    }
    __syncthreads();

    // ---- QK^T : c[mt][nt] = Q-tile @ M-tile^T ----
    U4BF bfm[2][4];
#pragma unroll
    for (int nt = 0; nt < 2; ++nt)
#pragma unroll
      for (int k = 0; k < 4; ++k)
        bfm[nt][k].u = *(const uint4*)&lds_M[nt * 16 + li][k * 32 + q * 8];

    v4f c[2][2];
    c[0][0] = zero4; c[0][1] = zero4; c[1][0] = zero4; c[1][1] = zero4;
#pragma unroll
    for (int k = 0; k < 4; ++k)
#pragma unroll
      for (int mt = 0; mt < 2; ++mt)
#pragma unroll
        for (int nt = 0; nt < 2; ++nt)
          c[mt][nt] = __builtin_amdgcn_mfma_f32_16x16x32_bf16(qf[mt][k].b, bfm[nt][k].b, c[mt][nt], 0, 0, 0);

    // ---- P = exp(relu(score) * A); accumulate sumE; stage P to LDS ----
#pragma unroll
    for (int mt = 0; mt < 2; ++mt)
#pragma unroll
      for (int nt = 0; nt < 2; ++nt) {
        int sloc = nt * 16 + li;
        float vmask = ((s0 + sloc) < S_TOT) ? 1.f : 0.f;
        const float4 a4 = *(const float4*)&lds_At[sloc][mt * 16 + q * 4];
        float aarr[4] = {a4.x, a4.y, a4.z, a4.w};
#pragma unroll
        for (int r = 0; r < 4; ++r) {
          float sc = fmaxf(c[mt][nt][r], 0.f) * aarr[r];
          float p = __expf(sc) * vmask;
          sE[mt][r] += p;
          lds_P[w * 32 + mt * 16 + q * 4 + r][sloc] = f2bf(p);
        }
      }
    __syncthreads();

    // ---- PV : acc[mt][dt] += P-tile @ M-tile ----
    U4BF pf[2];
#pragma unroll
    for (int mt = 0; mt < 2; ++mt)
      pf[mt].u = *(const uint4*)&lds_P[w * 32 + mt * 16 + li][q * 8];
#pragma unroll
    for (int dt = 0; dt < 8; ++dt) {
      U4BF mf;
      mf.u = *(const uint4*)&lds_Mt[dt * 16 + li][q * 8];
#pragma unroll
      for (int mt = 0; mt < 2; ++mt)
        acc[mt][dt] = __builtin_amdgcn_mfma_f32_16x16x32_bf16(pf[mt].b, mf.b, acc[mt][dt], 0, 0, 0);
    }
    __syncthreads();
  }

  // ---- write partials ----
  long base = ((long)ch * NBT + bt) * 256;
#pragma unroll
  for (int mt = 0; mt < 2; ++mt)
#pragma unroll
    for (int dt = 0; dt < 8; ++dt)
#pragma unroll
      for (int r = 0; r < 4; ++r) {
        int m = w * 32 + mt * 16 + q * 4 + r;
        part_acc[(base + m) * DDIM + dt * 16 + li] = acc[mt][dt][r];
      }
#pragma unroll
  for (int mt = 0; mt < 2; ++mt)
#pragma unroll
    for (int r = 0; r < 4; ++r) {
      float v = sE[mt][r];
      v += __shfl_xor(v, 1);
      v += __shfl_xor(v, 2);
      v += __shfl_xor(v, 4);
      v += __shfl_xor(v, 8);
      if (li == 0) part_sum[base + w * 32 + mt * 16 + q * 4 + r] = v;
    }
}

// ---------------------------------------------------------------- k_reduce
__global__ void k_reduce(const float* __restrict__ part_acc, const float* __restrict__ part_sum,
                         float* __restrict__ hhat) {
  int g = blockIdx.x * 256 + threadIdx.x;  // < 32*256*128
  int bt = g >> 15;
  int m = (g >> 7) & 255;
  int e = g & 127;
  float a = 0.f, s = 0.f;
#pragma unroll
  for (int ch = 0; ch < NCH; ++ch) {
    long base = ((long)ch * NBT + bt) * 256 + m;
    a += part_acc[base * DDIM + e];
    s += part_sum[base];
  }
  int h = m >> 5, bl = m & 31;
  int b = bt * BQ + bl;
  hhat[(long)b * 1024 + h * DDIM + e] = a / s;
}

// ---------------------------------------------------------------- k_final
__global__ void k_final(const float* __restrict__ hhat, const float* __restrict__ W1,
                        const int* __restrict__ uid, const float* __restrict__ user_emb,
                        float* __restrict__ out) {
  int blk = blockIdx.x;            // 64 blocks, 16 b-rows each
  int d = threadIdx.x & 127;
  int half = threadIdx.x >> 7;     // 0/1 (wave-uniform)
  int b0 = blk * 16 + half * 8;
  float acc[8] = {0.f,0.f,0.f,0.f,0.f,0.f,0.f,0.f};
  for (int k = 0; k < 1024; ++k) {
    float wv = W1[(long)k * DDIM + d];
#pragma unroll
    for (int j = 0; j < 8; ++j) acc[j] += hhat[(long)(b0 + j) * 1024 + k] * wv;
  }
#pragma unroll
  for (int j = 0; j < 8; ++j) {
    int b = b0 + j;
    float x = acc[j];
    float e = (x > 0.f) ? x : expm1f(x);
    out[(long)b * DDIM + d] = e + user_emb[(long)uid[b] * DDIM + d];
  }
}

// ---------------------------------------------------------------- launch
extern "C" void kernel_launch(void* const* d_in, const int* in_sizes, int n_in,
                              void* d_out, int out_size, void* d_ws, size_t ws_size,
                              hipStream_t stream) {
  const int* uid        = (const int*)d_in[0];
  const float* user_emb = (const float*)d_in[1];
  const float* src_emb  = (const float*)d_in[2];
  const float* Wcm      = (const float*)d_in[3];
  const float* W1       = (const float*)d_in[4];
  const float* A_us     = (const float*)d_in[5];
  float* out = (float*)d_out;

  char* ws = (char*)d_ws;
  // workspace layout (bytes)
  unsigned short* Qbf  = (unsigned short*)(ws + 0);          //  2,097,152
  unsigned short* Mbf  = (unsigned short*)(ws + 2097152);    // 12,877,824
  unsigned short* MbfT = (unsigned short*)(ws + 14974976);   // 12,877,824
  float* part_acc      = (float*)(ws + 27852800);            // 33,554,432
  float* part_sum      = (float*)(ws + 61407232);            //    262,144
  float* hhat          = (float*)(ws + 61669376);            //  4,194,304  (end ~65.9MB)

  k_qproj<<<dim3(NB * NHEAD), dim3(128), 0, stream>>>(uid, user_emb, Wcm, Qbf);
  k_convM<<<dim3((S_PAD * DDIM / 8 + 255) / 256), dim3(256), 0, stream>>>(src_emb, Mbf);
  k_transM<<<dim3(S_PAD / 64, DDIM / 64), dim3(256), 0, stream>>>(Mbf, MbfT);
  k_attn<<<dim3(NCH, NBT), dim3(512), 0, stream>>>(uid, A_us, Qbf, Mbf, MbfT, part_acc, part_sum);
  k_reduce<<<dim3(NBT * 256 * DDIM / 256), dim3(256), 0, stream>>>(part_acc, part_sum, hhat);
  k_final<<<dim3(64), dim3(256), 0, stream>>>(hhat, W1, uid, user_emb, out);
}

// Round 2
// 1077.504 us; speedup vs baseline: 1.0128x; 1.0128x over previous
//
#include <hip/hip_runtime.h>
#include <hip/hip_bf16.h>
#include <math.h>

// ---------------------------------------------------------------------------
// FakeNewsAttention round 2: occupancy fix (512 blocks = 2 blocks/CU),
// double-buffered staging (2 syncs/iter), truncation bf16, bf16 partials.
// ---------------------------------------------------------------------------

#define S_TOT 50000
#define S_PAD 50304   // multiple of 64
#define DDIM 128
#define NHEAD 8
#define NB 1024
#define BQ 32         // batch rows per attention block
#define SN 32         // sources per inner iteration
#define NCH 16        // S chunks  -> grid = 16*32 = 512 blocks = 2/CU
#define SCHUNK 3136   // 16*3136 = 50176 >= 50000, multiple of 32
#define NIT (SCHUNK / SN)   // 98
#define NBT 32        // NB / BQ
#define PAD_CNT 176.0f      // 50176 - 50000 pad sources contribute exp(0)=1 each

typedef __bf16 v8bf __attribute__((ext_vector_type(8)));
typedef float v4f __attribute__((ext_vector_type(4)));

union U4BF { uint4 u; v8bf b; };

__device__ inline unsigned short f2bf(float f) {
  union { float f; unsigned u; } v; v.f = f;
  unsigned r = (v.u + 0x7FFFu + ((v.u >> 16) & 1u)) >> 16;
  return (unsigned short)r;
}

// ---------------------------------------------------------------- k_qproj
__global__ void k_qproj(const int* __restrict__ uid, const float* __restrict__ user_emb,
                        const float* __restrict__ Wcm, unsigned short* __restrict__ Qbf) {
  int bh = blockIdx.x;          // b*8 + h
  int b = bh >> 3, h = bh & 7;
  int e = threadIdx.x;          // 0..127
  int u = uid[b];
  const float* xu = user_emb + (long)u * DDIM;
  const float* w = Wcm + (long)h * DDIM * DDIM + e;
  float acc = 0.f;
#pragma unroll 16
  for (int d = 0; d < DDIM; ++d) acc += xu[d] * w[(long)d * DDIM];
  Qbf[(long)bh * DDIM + e] = f2bf(acc * 0.08838834764831845f); // 1/sqrt(128)
}

// ---------------------------------------------------------------- k_prepM
// fused: float M -> bf16 row-major Mbf (padded) + bf16 transposed MbfT
__global__ void k_prepM(const float* __restrict__ M, unsigned short* __restrict__ Mbf,
                        unsigned short* __restrict__ MbfT) {
  __shared__ unsigned short tile[64][66];   // 66: stride 132B = 33 banks -> 2-way free
  int s0 = blockIdx.x * 64, d0 = blockIdx.y * 64;
  int t = threadIdx.x;
#pragma unroll
  for (int it = 0; it < 16; ++it) {
    int flat = t + 256 * it;               // 0..4095
    int sl = flat >> 6, dl = flat & 63;
    int s = s0 + sl;
    float v = (s < S_TOT) ? M[(long)s * DDIM + d0 + dl] : 0.f;
    unsigned short bb = f2bf(v);
    tile[sl][dl] = bb;
    Mbf[(long)s * DDIM + d0 + dl] = bb;
  }
  __syncthreads();
#pragma unroll
  for (int it = 0; it < 16; ++it) {
    int flat = t + 256 * it;
    int dl = flat >> 6, sl = flat & 63;
    MbfT[(long)(d0 + dl) * S_PAD + s0 + sl] = tile[sl][dl];
  }
}

// ---------------------------------------------------------------- k_attn
// 512 threads = 8 waves; wave w == head w; BQ=32 batch rows; double-buffered
// staging; 2 syncs per SN=32 source iteration.
__launch_bounds__(512, 4)
__global__ void k_attn(const int* __restrict__ uid_g, const float* __restrict__ A_us,
                       const unsigned short* __restrict__ Qbf,
                       const unsigned short* __restrict__ Mbf,
                       const unsigned short* __restrict__ MbfT,
                       unsigned short* __restrict__ part_acc, float* __restrict__ part_sum) {
  __shared__ __align__(16) unsigned short lds_M[2][SN][136];    // 17.4 KB
  __shared__ __align__(16) unsigned short lds_Mt[2][DDIM][40];  // 20.5 KB
  __shared__ __align__(16) unsigned short lds_P[256][40];       // 20.5 KB
  __shared__ __align__(16) float lds_At[2][SN][36];             //  9.2 KB
  __shared__ int lds_uid[BQ];                                   // total ~68 KB -> 2 blocks/CU

  const int ch = blockIdx.x;   // 0..NCH-1
  const int bt = blockIdx.y;   // 0..NBT-1
  const int tid = threadIdx.x;
  const int w = tid >> 6;      // wave id == head
  const int lane = tid & 63;
  const int q = lane >> 4, li = lane & 15;

  if (tid < BQ) lds_uid[tid] = uid_g[bt * BQ + tid];

  // Q fragments (A-operand): qf[mt][k] -> Q[b0 + mt*16 + li][k*32 + q*8 .. +7]
  U4BF qf[2][4];
#pragma unroll
  for (int mt = 0; mt < 2; ++mt)
#pragma unroll
    for (int k = 0; k < 4; ++k) {
      int b = bt * BQ + mt * 16 + li;
      qf[mt][k].u = *(const uint4*)(Qbf + ((long)(b * NHEAD + w) * DDIM + k * 32 + q * 8));
    }

  v4f zero4 = {0.f, 0.f, 0.f, 0.f};
  v4f acc[2][8];
#pragma unroll
  for (int mt = 0; mt < 2; ++mt)
#pragma unroll
    for (int dt = 0; dt < 8; ++dt) acc[mt][dt] = zero4;
  float sE[2][4] = {{0.f,0.f,0.f,0.f},{0.f,0.f,0.f,0.f}};

  __syncthreads();   // lds_uid visible

  const int s_beg = ch * SCHUNK;

  auto stage = [&](int buf, int s0) {
    int sl = tid >> 4, d = (tid & 15) * 8;
    *(uint4*)&lds_M[buf][sl][d] = *(const uint4*)(Mbf + (long)(s0 + sl) * DDIM + d);
    int dd = tid >> 2, pp = (tid & 3) * 8;
    *(uint4*)&lds_Mt[buf][dd][pp] = *(const uint4*)(MbfT + (long)dd * S_PAD + s0 + pp);
    if (tid < 256) {
      int bl = tid >> 3, sq = (tid & 7) * 4;
      const float* arow = A_us + (long)lds_uid[bl] * S_TOT;
      int sg = s0 + sq;
      float4 av;
      if (sg + 3 < S_TOT) {
        av = *(const float4*)(arow + sg);
      } else {
        av.x = (sg + 0 < S_TOT) ? arow[sg + 0] : 0.f;
        av.y = (sg + 1 < S_TOT) ? arow[sg + 1] : 0.f;
        av.z = (sg + 2 < S_TOT) ? arow[sg + 2] : 0.f;
        av.w = (sg + 3 < S_TOT) ? arow[sg + 3] : 0.f;
      }
      lds_At[buf][sq + 0][bl] = av.x;
      lds_At[buf][sq + 1][bl] = av.y;
      lds_At[buf][sq + 2][bl] = av.z;
      lds_At[buf][sq + 3][bl] = av.w;
    }
  };

  stage(0, s_beg);
  __syncthreads();

  for (int it = 0; it < NIT; ++it) {
    const int p = it & 1;
    const int s0 = s_beg + it * SN;
    if (it + 1 < NIT) stage(1 - p, s0 + SN);   // prefetch next while computing

    // ---- QK^T from buf p ----
    U4BF bfm[2][4];
#pragma unroll
    for (int nt = 0; nt < 2; ++nt)
#pragma unroll
      for (int k = 0; k < 4; ++k)
        bfm[nt][k].u = *(const uint4*)&lds_M[p][nt * 16 + li][k * 32 + q * 8];

    v4f c[2][2];
    c[0][0] = zero4; c[0][1] = zero4; c[1][0] = zero4; c[1][1] = zero4;
#pragma unroll
    for (int k = 0; k < 4; ++k)
#pragma unroll
      for (int mt = 0; mt < 2; ++mt)
#pragma unroll
        for (int nt = 0; nt < 2; ++nt)
          c[mt][nt] = __builtin_amdgcn_mfma_f32_16x16x32_bf16(qf[mt][k].b, bfm[nt][k].b, c[mt][nt], 0, 0, 0);

    // ---- P = exp(relu(score)*A); pad sources give exp(0)=1, fixed in reduce ----
#pragma unroll
    for (int mt = 0; mt < 2; ++mt)
#pragma unroll
      for (int nt = 0; nt < 2; ++nt) {
        int sloc = nt * 16 + li;
        const float4 a4 = *(const float4*)&lds_At[p][sloc][mt * 16 + q * 4];
        float aarr[4] = {a4.x, a4.y, a4.z, a4.w};
#pragma unroll
        for (int r = 0; r < 4; ++r) {
          float sc = fmaxf(c[mt][nt][r], 0.f) * aarr[r];
          float pv = __expf(sc);
          sE[mt][r] += pv;
          lds_P[w * 32 + mt * 16 + q * 4 + r][sloc] =
              (unsigned short)(__float_as_uint(pv) >> 16);  // truncation: bias cancels in ratio
        }
      }
    __syncthreads();   // P ready; next-buf staging complete

    // ---- PV ----
    U4BF pf[2];
#pragma unroll
    for (int mt = 0; mt < 2; ++mt)
      pf[mt].u = *(const uint4*)&lds_P[w * 32 + mt * 16 + li][q * 8];
#pragma unroll
    for (int dt = 0; dt < 8; ++dt) {
      U4BF mf;
      mf.u = *(const uint4*)&lds_Mt[p][dt * 16 + li][q * 8];
#pragma unroll
      for (int mt = 0; mt < 2; ++mt)
        acc[mt][dt] = __builtin_amdgcn_mfma_f32_16x16x32_bf16(pf[mt].b, mf.b, acc[mt][dt], 0, 0, 0);
    }
    __syncthreads();   // PV done reading buf p / lds_P before they are overwritten
  }

  // ---- write partials (bf16 acc, f32 sums) ----
  long base = ((long)ch * NBT + bt) * 256;
#pragma unroll
  for (int mt = 0; mt < 2; ++mt)
#pragma unroll
    for (int dt = 0; dt < 8; ++dt)
#pragma unroll
      for (int r = 0; r < 4; ++r) {
        int m = w * 32 + mt * 16 + q * 4 + r;
        part_acc[(base + m) * DDIM + dt * 16 + li] = f2bf(acc[mt][dt][r]);
      }
#pragma unroll
  for (int mt = 0; mt < 2; ++mt)
#pragma unroll
    for (int r = 0; r < 4; ++r) {
      float v = sE[mt][r];
      v += __shfl_xor(v, 1);
      v += __shfl_xor(v, 2);
      v += __shfl_xor(v, 4);
      v += __shfl_xor(v, 8);
      if (li == 0) part_sum[base + w * 32 + mt * 16 + q * 4 + r] = v;
    }
}

// ---------------------------------------------------------------- k_reduce
__global__ void k_reduce(const unsigned short* __restrict__ part_acc,
                         const float* __restrict__ part_sum, float* __restrict__ hhat) {
  int g = blockIdx.x * 256 + threadIdx.x;  // < 32*256*128
  int bt = g >> 15;
  int m = (g >> 7) & 255;
  int e = g & 127;
  float a = 0.f, s = 0.f;
#pragma unroll
  for (int ch = 0; ch < NCH; ++ch) {
    long base = ((long)ch * NBT + bt) * 256 + m;
    unsigned ub = part_acc[base * DDIM + e];
    a += __uint_as_float(ub << 16);
    s += part_sum[base];
  }
  s -= PAD_CNT;   // pad sources contributed exp(0)=1 each
  int h = m >> 5, bl = m & 31;
  int b = bt * BQ + bl;
  hhat[(long)b * 1024 + h * DDIM + e] = a / s;
}

// ---------------------------------------------------------------- k_final
__global__ void k_final(const float* __restrict__ hhat, const float* __restrict__ W1,
                        const int* __restrict__ uid, const float* __restrict__ user_emb,
                        float* __restrict__ out) {
  int blk = blockIdx.x;            // 256 blocks, 4 b-rows each (2 per half)
  int d = threadIdx.x & 127;
  int half = threadIdx.x >> 7;     // wave-uniform
  int b0 = blk * 4 + half * 2;
  float a0 = 0.f, a1 = 0.f;
  const float* h0 = hhat + (long)b0 * 1024;
  const float* h1 = h0 + 1024;
#pragma unroll 8
  for (int k = 0; k < 1024; ++k) {
    float wv = W1[(long)k * DDIM + d];
    a0 += h0[k] * wv;
    a1 += h1[k] * wv;
  }
  float e0 = (a0 > 0.f) ? a0 : expm1f(a0);
  float e1 = (a1 > 0.f) ? a1 : expm1f(a1);
  out[(long)b0 * DDIM + d]         = e0 + user_emb[(long)uid[b0] * DDIM + d];
  out[(long)(b0 + 1) * DDIM + d]   = e1 + user_emb[(long)uid[b0 + 1] * DDIM + d];
}

// ---------------------------------------------------------------- launch
extern "C" void kernel_launch(void* const* d_in, const int* in_sizes, int n_in,
                              void* d_out, int out_size, void* d_ws, size_t ws_size,
                              hipStream_t stream) {
  const int* uid        = (const int*)d_in[0];
  const float* user_emb = (const float*)d_in[1];
  const float* src_emb  = (const float*)d_in[2];
  const float* Wcm      = (const float*)d_in[3];
  const float* W1       = (const float*)d_in[4];
  const float* A_us     = (const float*)d_in[5];
  float* out = (float*)d_out;

  char* ws = (char*)d_ws;
  // workspace layout (bytes), total ~66.1 MB
  unsigned short* Qbf      = (unsigned short*)(ws + 0);          //  2,097,152
  unsigned short* Mbf      = (unsigned short*)(ws + 2097152);    // 12,877,824
  unsigned short* MbfT     = (unsigned short*)(ws + 14974976);   // 12,877,824
  unsigned short* part_acc = (unsigned short*)(ws + 27852800);   // 33,554,432 (bf16)
  float* part_sum          = (float*)(ws + 61407232);            //    524,288
  float* hhat              = (float*)(ws + 61931520);            //  4,194,304 -> 66,125,824

  k_qproj<<<dim3(NB * NHEAD), dim3(128), 0, stream>>>(uid, user_emb, Wcm, Qbf);
  k_prepM<<<dim3(S_PAD / 64, DDIM / 64), dim3(256), 0, stream>>>(src_emb, Mbf, MbfT);
  k_attn<<<dim3(NCH, NBT), dim3(512), 0, stream>>>(uid, A_us, Qbf, Mbf, MbfT, part_acc, part_sum);
  k_reduce<<<dim3(NBT * 256 * DDIM / 256), dim3(256), 0, stream>>>(part_acc, part_sum, hhat);
  k_final<<<dim3(256), dim3(256), 0, stream>>>(hhat, W1, uid, user_emb, out);
}